// Round 16
// baseline (165.861 us; speedup 1.0000x reference)
//
#include <hip/hip_runtime.h>

// Problem constants (from reference setup_inputs): B=8, L=4096, D=256, f32.
#define BATCH 8
#define SEQ   4096
#define DIM   256

typedef float floatx4 __attribute__((ext_vector_type(4)));

// R16: single fused kernel. NT=64 tiles/batch, T=64. 512 tiles, 256 blocks
// (2 tiles/block, R8's 128-thread/2-col half-tile shape). All blocks
// co-resident (256 << capacity) -> flag spin is deadlock-free.
// Phase A: per-column tile aggregate (product chain + y-from-zero).
// Publish aggregates (relaxed agent atomics) + release flag.
// Phase B: wait for predecessors' flags (they finish ~simultaneously),
// read ALL <=63 predecessor aggregates in PARALLEL, compose locally
// (fixes R12's serial inclusive-frontier catastrophe).
// Phase C: recompute recurrence from seed on L2/L3-hot data, store out.
// Eliminates: 2 launch gaps, k2 dispatch, 42MB agg/seed HBM round-trips.

constexpr int NT_F   = 64;                 // tiles per batch
constexpr int T_F    = SEQ / NT_F;         // 64 steps per tile
constexpr int NTILES_F = BATCH * NT_F;     // 512
constexpr size_t VAGG_OFF = 4096;
constexpr size_t WS_NEED_F = VAGG_OFF + (size_t)NTILES_F * DIM * 16;  // ~2.1MB

__device__ __forceinline__ unsigned long long pack2f(float a, float b) {
    union { float f[2]; unsigned long long u; } u_;
    u_.f[0] = a; u_.f[1] = b; return u_.u;
}
__device__ __forceinline__ void unpack2f(unsigned long long u, float& a, float& b) {
    union { unsigned long long u; float f[2]; } u_;
    u_.u = u; a = u_.f[0]; b = u_.f[1];
}

__global__ __launch_bounds__(256) void k_fused(
    const float* __restrict__ Ar, const float* __restrict__ Ai,
    const float* __restrict__ Xr, const float* __restrict__ Xi,
    float* __restrict__ outf,
    unsigned* __restrict__ flags, unsigned long long* __restrict__ vagg)
{
    __shared__ float4 s_ag[128][2];        // tile j0 (half 0) aggregates
    constexpr int NT = NT_F, T = T_F;

    int half = threadIdx.x >> 7;           // 0/1 -> tile j0 / j0+1
    int wl   = threadIdx.x & 127;
    int tile = blockIdx.x * 2 + half;      // j0 even, halves share b
    int b  = tile / NT;
    int j  = tile - b * NT;
    int j0 = j & ~1;                       // half-0 tile index
    int d0 = wl * 2;

    size_t base = ((size_t)b * SEQ + (size_t)j * T) * DIM + d0;

    // ---- Phase A: tile aggregate, 2 cols/thread, float2 loads ----
    float pr[2], pi[2], yr[2], yi[2];
#pragma unroll
    for (int c = 0; c < 2; ++c) { pr[c] = 1.f; pi[c] = 0.f; yr[c] = 0.f; yi[c] = 0.f; }

#pragma unroll 4
    for (int t = 0; t < T; ++t) {
        size_t idx = base + (size_t)t * DIM;
        float2 a_re = *(const float2*)(Ar + idx);
        float2 a_im = *(const float2*)(Ai + idx);
        float2 x_re = *(const float2*)(Xr + idx);
        float2 x_im = *(const float2*)(Xi + idx);
        const float* par = (const float*)&a_re;
        const float* pai = (const float*)&a_im;
        const float* pxr = (const float*)&x_re;
        const float* pxi = (const float*)&x_im;
#pragma unroll
        for (int c = 0; c < 2; ++c) {
            float a_r = par[c], a_i = pai[c];
            float npr = a_r * pr[c] - a_i * pi[c];
            float npi = a_r * pi[c] + a_i * pr[c];
            pr[c] = npr; pi[c] = npi;
            float nyr = a_r * yr[c] - a_i * yi[c] + pxr[c];
            float nyi = a_r * yi[c] + a_i * yr[c] + pxi[c];
            yr[c] = nyr; yi[c] = nyi;
        }
    }

    // ---- Publish aggregates; stash half-0's in LDS for half 1 ----
#pragma unroll
    for (int c = 0; c < 2; ++c) {
        size_t vs = 2 * ((size_t)tile * DIM + d0 + c);
        __hip_atomic_store(&vagg[vs + 0], pack2f(pr[c], pi[c]),
                           __ATOMIC_RELAXED, __HIP_MEMORY_SCOPE_AGENT);
        __hip_atomic_store(&vagg[vs + 1], pack2f(yr[c], yi[c]),
                           __ATOMIC_RELAXED, __HIP_MEMORY_SCOPE_AGENT);
    }
    if (half == 0) {
        s_ag[wl][0] = make_float4(pr[0], pi[0], yr[0], yi[0]);
        s_ag[wl][1] = make_float4(pr[1], pi[1], yr[1], yi[1]);
    }
    __threadfence();
    __syncthreads();
    if (threadIdx.x == 0) {
        __hip_atomic_store(&flags[tile],     1u, __ATOMIC_RELEASE, __HIP_MEMORY_SCOPE_AGENT);
        __hip_atomic_store(&flags[tile + 1], 1u, __ATOMIC_RELEASE, __HIP_MEMORY_SCOPE_AGENT);
    }

    // ---- Phase B: wait for predecessors 0..j0-1 (parallel aggregates) ----
    if (threadIdx.x == 0) {
        for (int k = 0; k < j0; ++k) {
            while (__hip_atomic_load(&flags[b * NT + k], __ATOMIC_ACQUIRE,
                                     __HIP_MEMORY_SCOPE_AGENT) == 0u)
                __builtin_amdgcn_s_sleep(1);
        }
    }
    __syncthreads();

    // Compose predecessors 0..j0-1 forward; seed = x-part of composite.
    float car[2], cai[2], cxr[2], cxi[2];
#pragma unroll
    for (int c = 0; c < 2; ++c) { car[c] = 1.f; cai[c] = 0.f; cxr[c] = 0.f; cxi[c] = 0.f; }

    for (int k = 0; k < j0; ++k) {
#pragma unroll
        for (int c = 0; c < 2; ++c) {
            size_t ps = 2 * ((size_t)(b * NT + k) * DIM + d0 + c);
            unsigned long long w0 = __hip_atomic_load(&vagg[ps + 0], __ATOMIC_RELAXED, __HIP_MEMORY_SCOPE_AGENT);
            unsigned long long w1 = __hip_atomic_load(&vagg[ps + 1], __ATOMIC_RELAXED, __HIP_MEMORY_SCOPE_AGENT);
            float ar_, ai_, xr_, xi_;
            unpack2f(w0, ar_, ai_);
            unpack2f(w1, xr_, xi_);
            // composite' = combine(left=composite, right=tile k)
            float nar = ar_ * car[c] - ai_ * cai[c];
            float nai = ar_ * cai[c] + ai_ * car[c];
            float nxr = ar_ * cxr[c] - ai_ * cxi[c] + xr_;
            float nxi = ar_ * cxi[c] + ai_ * cxr[c] + xi_;
            car[c] = nar; cai[c] = nai; cxr[c] = nxr; cxi[c] = nxi;
        }
    }
    if (half == 1) {
        // fold in local tile j0 from LDS
#pragma unroll
        for (int c = 0; c < 2; ++c) {
            float4 v = s_ag[wl][c];
            float nar = v.x * car[c] - v.y * cai[c];
            float nai = v.x * cai[c] + v.y * car[c];
            float nxr = v.x * cxr[c] - v.y * cxi[c] + v.z;
            float nxi = v.x * cxi[c] + v.y * cxr[c] + v.w;
            car[c] = nar; cai[c] = nai; cxr[c] = nxr; cxi[c] = nxi;
        }
    }

    // ---- Phase C: apply from seed on cache-hot data, store [B,L,D,2] ----
    float fy_r[2] = {cxr[0], cxr[1]};
    float fy_i[2] = {cxi[0], cxi[1]};
#pragma unroll 4
    for (int t = 0; t < T; ++t) {
        size_t idx = base + (size_t)t * DIM;
        float2 a_re = *(const float2*)(Ar + idx);
        float2 a_im = *(const float2*)(Ai + idx);
        float2 x_re = *(const float2*)(Xr + idx);
        float2 x_im = *(const float2*)(Xi + idx);
        const float* par = (const float*)&a_re;
        const float* pai = (const float*)&a_im;
        const float* pxr = (const float*)&x_re;
        const float* pxi = (const float*)&x_im;
#pragma unroll
        for (int c = 0; c < 2; ++c) {
            float nyr = par[c] * fy_r[c] - pai[c] * fy_i[c] + pxr[c];
            float nyi = par[c] * fy_i[c] + pai[c] * fy_r[c] + pxi[c];
            fy_r[c] = nyr; fy_i[c] = nyi;
        }
        *(float4*)(outf + 2 * idx) =
            make_float4(fy_r[0], fy_i[0], fy_r[1], fy_i[1]);
    }
}

// ===========================================================================
// Fallback 3-kernel path (tiny workspace) — NT=64, R10 forms.
// ===========================================================================
template <int NT, int T>
__global__ __launch_bounds__(256) void k_tile_agg_fb(
    const float* __restrict__ Ar, const float* __restrict__ Ai,
    const float* __restrict__ Xr, const float* __restrict__ Xi,
    float4* __restrict__ agg)
{
    int wave = threadIdx.x >> 6;
    int lane = threadIdx.x & 63;
    int tile = blockIdx.x * 4 + wave;
    int b = tile / NT;
    int j = tile - b * NT;
    int d = lane * 4;

    size_t base = ((size_t)b * SEQ + (size_t)j * T) * DIM + d;

    float pr[4], pi[4], yr[4], yi[4];
#pragma unroll
    for (int k = 0; k < 4; ++k) { pr[k] = 1.f; pi[k] = 0.f; yr[k] = 0.f; yi[k] = 0.f; }

#pragma unroll 4
    for (int t = 0; t < T; ++t) {
        size_t idx = base + (size_t)t * DIM;
        float4 a_re = *(const float4*)(Ar + idx);
        float4 a_im = *(const float4*)(Ai + idx);
        float4 x_re = *(const float4*)(Xr + idx);
        float4 x_im = *(const float4*)(Xi + idx);
        const float* par = (const float*)&a_re;
        const float* pai = (const float*)&a_im;
        const float* pxr = (const float*)&x_re;
        const float* pxi = (const float*)&x_im;
#pragma unroll
        for (int k = 0; k < 4; ++k) {
            float a_r = par[k], a_i = pai[k];
            float npr = a_r * pr[k] - a_i * pi[k];
            float npi = a_r * pi[k] + a_i * pr[k];
            pr[k] = npr; pi[k] = npi;
            float nyr = a_r * yr[k] - a_i * yi[k] + pxr[k];
            float nyi = a_r * yi[k] + a_i * yr[k] + pxi[k];
            yr[k] = nyr; yi[k] = nyi;
        }
    }

    size_t o = ((size_t)b * NT + j) * DIM + d;
#pragma unroll
    for (int k = 0; k < 4; ++k)
        agg[o + k] = make_float4(pr[k], pi[k], yr[k], yi[k]);
}

template <int NT>
__global__ __launch_bounds__(256) void k_scan_agg_fb(float4* __restrict__ agg)
{
    constexpr int NTPL = NT / 64;
    int lane = threadIdx.x & 63;
    int col  = blockIdx.x * 4 + (threadIdx.x >> 6);
    int b = col >> 8;
    int d = col & 255;

    float4 v[NTPL];
    float lar = 1.f, lai = 0.f, lxr = 0.f, lxi = 0.f;
#pragma unroll
    for (int m = 0; m < NTPL; ++m) {
        v[m] = agg[((size_t)b * NT + lane * NTPL + m) * DIM + d];
        float nar = v[m].x * lar - v[m].y * lai;
        float nai = v[m].x * lai + v[m].y * lar;
        float nxr = v[m].x * lxr - v[m].y * lxi + v[m].z;
        float nxi = v[m].x * lxi + v[m].y * lxr + v[m].w;
        lar = nar; lai = nai; lxr = nxr; lxi = nxi;
    }

    float ar = lar, ai = lai, xr = lxr, xi = lxi;
#pragma unroll
    for (int off = 1; off < 64; off <<= 1) {
        float par = __shfl_up(ar, (unsigned)off, 64);
        float pai = __shfl_up(ai, (unsigned)off, 64);
        float pxr = __shfl_up(xr, (unsigned)off, 64);
        float pxi = __shfl_up(xi, (unsigned)off, 64);
        if (lane >= off) {
            float nar = ar * par - ai * pai;
            float nai = ar * pai + ai * par;
            float nxr = ar * pxr - ai * pxi + xr;
            float nxi = ar * pxi + ai * pxr + xi;
            ar = nar; ai = nai; xr = nxr; xi = nxi;
        }
    }

    float ear = __shfl_up(ar, 1u, 64);
    float eai = __shfl_up(ai, 1u, 64);
    float exr = __shfl_up(xr, 1u, 64);
    float exi = __shfl_up(xi, 1u, 64);
    if (lane == 0) { ear = 1.f; eai = 0.f; exr = 0.f; exi = 0.f; }

#pragma unroll
    for (int m = 0; m < NTPL; ++m) {
        agg[((size_t)b * NT + lane * NTPL + m) * DIM + d] =
            make_float4(exr, exi, 0.f, 0.f);
        float nar = v[m].x * ear - v[m].y * eai;
        float nai = v[m].x * eai + v[m].y * ear;
        float nxr = v[m].x * exr - v[m].y * exi + v[m].z;
        float nxi = v[m].x * exi + v[m].y * exr + v[m].w;
        ear = nar; eai = nai; exr = nxr; exi = nxi;
    }
}

template <int NT, int T>
__global__ __launch_bounds__(256, 8) void k_apply_fb(
    const float* __restrict__ Ar, const float* __restrict__ Ai,
    const float* __restrict__ Xr, const float* __restrict__ Xi,
    const float4* __restrict__ agg, float* __restrict__ outf)
{
    int half = threadIdx.x >> 7;
    int wl   = threadIdx.x & 127;
    int tile = blockIdx.x * 2 + half;
    int b = tile / NT;
    int j = tile - b * NT;
    int d = wl * 2;

    float yr[2], yi[2];
    size_t o = ((size_t)b * NT + j) * DIM + d;
    {
        float4 p0 = agg[o];
        float4 p1 = agg[o + 1];
        yr[0] = p0.x; yi[0] = p0.y;
        yr[1] = p1.x; yi[1] = p1.y;
    }

    size_t base = ((size_t)b * SEQ + (size_t)j * T) * DIM + d;

#pragma unroll
    for (int t = 0; t < T; ++t) {
        size_t idx = base + (size_t)t * DIM;
        float2 a_re = *(const float2*)(Ar + idx);
        float2 a_im = *(const float2*)(Ai + idx);
        float2 x_re = *(const float2*)(Xr + idx);
        float2 x_im = *(const float2*)(Xi + idx);
        const float* par = (const float*)&a_re;
        const float* pai = (const float*)&a_im;
        const float* pxr = (const float*)&x_re;
        const float* pxi = (const float*)&x_im;
#pragma unroll
        for (int k = 0; k < 2; ++k) {
            float nyr = par[k] * yr[k] - pai[k] * yi[k] + pxr[k];
            float nyi = par[k] * yi[k] + pai[k] * yr[k] + pxi[k];
            yr[k] = nyr; yi[k] = nyi;
        }
        *(float4*)(outf + 2 * idx) = make_float4(yr[0], yi[0], yr[1], yi[1]);
    }
}

extern "C" void kernel_launch(void* const* d_in, const int* in_sizes, int n_in,
                              void* d_out, int out_size, void* d_ws, size_t ws_size,
                              hipStream_t stream)
{
    const float* Ar = (const float*)d_in[0];
    const float* Ai = (const float*)d_in[1];
    const float* Xr = (const float*)d_in[2];
    const float* Xi = (const float*)d_in[3];
    float* outf = (float*)d_out;

    if (ws_size >= WS_NEED_F) {
        unsigned* flags = (unsigned*)d_ws;
        unsigned long long* vagg =
            (unsigned long long*)((char*)d_ws + VAGG_OFF);
        // zero flags each launch (replay-safe, graph-capturable)
        hipMemsetAsync(d_ws, 0, VAGG_OFF, stream);
        k_fused<<<NTILES_F / 2, 256, 0, stream>>>(
            Ar, Ai, Xr, Xi, outf, flags, vagg);
    } else {
        float4* agg = (float4*)d_ws;
        constexpr int NT = 64, T = SEQ / 64;
        dim3 block(256);
        k_tile_agg_fb<NT, T><<<(BATCH * NT) / 4, block, 0, stream>>>(Ar, Ai, Xr, Xi, agg);
        k_scan_agg_fb<NT><<<(BATCH * DIM) / 4, block, 0, stream>>>(agg);
        k_apply_fb<NT, T><<<(BATCH * NT) / 2, block, 0, stream>>>(Ar, Ai, Xr, Xi, agg, outf);
    }
}

// Round 17
// 63.152 us; speedup vs baseline: 2.6264x; 2.6264x over previous
//
#include <hip/hip_runtime.h>

// Problem constants (from reference setup_inputs): B=8, L=4096, D=256, f32.
#define BATCH 8
#define SEQ   4096
#define DIM   256

typedef float floatx4 __attribute__((ext_vector_type(4)));

// R17 = R15 verbatim (best measured: 63.2us). Fused single-pass designs
// (R12 serial frontier, R16 parallel lookback) both lose >2x to the 3-pass
// structure; k1's ~1.65 TB/s L2-fill wall survived 10 falsification
// attempts. 3-pass floor ~55-60us; we are within ~10%.

constexpr int NT_MAIN = 256;
constexpr int T_MAIN  = SEQ / NT_MAIN;      // 16
constexpr int TSUB    = 4;                  // timesteps per staged subtile
constexpr int SUB_FLOATS = TSUB * DIM;      // 1024 floats = 4KB per array
constexpr int NSUB_BLK   = 8;               // subtiles per block (32 steps)
constexpr int NSUB_TOT   = BATCH * SEQ / TSUB;   // 8192
constexpr int SUB_PER_TILE = T_MAIN / TSUB; // 4 subtiles per agg tile

constexpr size_t AGG_BYTES  = (size_t)BATCH * NT_MAIN * DIM * 16;   // 16.8 MB
constexpr size_t SEED_BYTES = (size_t)BATCH * NT_MAIN * DIM * 8;    //  8.4 MB

// ---------------------------------------------------------------------------
// Kernel 1: persistent pipelined tile aggregates, 4 blocks/CU.
// ---------------------------------------------------------------------------
__global__ __launch_bounds__(256, 4) void k_tile_agg_pipe(
    const float* __restrict__ Ar, const float* __restrict__ Ai,
    const float* __restrict__ Xr, const float* __restrict__ Xi,
    float4* __restrict__ agg)
{
    __shared__ float lds[2][4][SUB_FLOATS];           // 32 KB

    int wave = threadIdx.x >> 6, lane = threadIdx.x & 63;
    int d = threadIdx.x;
    const float* src = (wave == 0) ? Ar : (wave == 1) ? Ai
                      : (wave == 2) ? Xr : Xi;

    int s0 = blockIdx.x * NSUB_BLK;                   // first global subtile
    const float* gsrc = src + (size_t)s0 * SUB_FLOATS + (size_t)lane * 4;

    auto ISSUE = [&](int i) {                         // stage subtile s0+i
        const float* g = gsrc + (size_t)i * SUB_FLOATS;
        float* l = &lds[i & 1][wave][0];              // wave-uniform dest
#pragma unroll
        for (int r = 0; r < TSUB; ++r) {
            __builtin_amdgcn_global_load_lds(
                (const __attribute__((address_space(1))) void*)(g + r * DIM),
                (__attribute__((address_space(3))) void*)(l + r * DIM),
                16, 0, 0);
        }
    };

    float pr = 1.f, pi = 0.f, yr = 0.f, yi = 0.f;

    ISSUE(0);
#pragma unroll 1
    for (int i = 0; i < NSUB_BLK; ++i) {
        if (i + 1 < NSUB_BLK) {
            ISSUE(i + 1);                              // keep next subtile in flight
            asm volatile("s_waitcnt vmcnt(4)" ::: "memory");   // subtile i done
        } else {
            asm volatile("s_waitcnt vmcnt(0)" ::: "memory");
        }
        __builtin_amdgcn_s_barrier();                  // all 4 arrays present
        __builtin_amdgcn_sched_barrier(0);

        const int buf = i & 1;
#pragma unroll
        for (int t = 0; t < TSUB; ++t) {
            float a_r = lds[buf][0][t * DIM + d];
            float a_i = lds[buf][1][t * DIM + d];
            float x_r = lds[buf][2][t * DIM + d];
            float x_i = lds[buf][3][t * DIM + d];
            float npr = a_r * pr - a_i * pi;
            float npi = a_r * pi + a_i * pr;
            pr = npr; pi = npi;
            float nyr = a_r * yr - a_i * yi + x_r;
            float nyi = a_r * yi + a_i * yr + x_i;
            yr = nyr; yi = nyi;
        }
        if ((i & (SUB_PER_TILE - 1)) == SUB_PER_TILE - 1) {   // tile finished
            int s = s0 + i;
            agg[(size_t)(s / SUB_PER_TILE) * DIM + d] = make_float4(pr, pi, yr, yi);
            pr = 1.f; pi = 0.f; yr = 0.f; yi = 0.f;
        }
        __builtin_amdgcn_s_barrier();                  // reads done before overwrite
    }
}

// ---------------------------------------------------------------------------
// Kernel 2: wave-parallel exclusive scan; emits float2 seed.
// ---------------------------------------------------------------------------
template <int NT>
__global__ __launch_bounds__(256) void k_scan_agg(
    float4* __restrict__ agg, float2* __restrict__ seed)
{
    constexpr int NTPL = NT / 64;
    int lane = threadIdx.x & 63;
    int col  = blockIdx.x * 4 + (threadIdx.x >> 6);   // in [0, BATCH*DIM)
    int b = col >> 8;
    int d = col & 255;

    float4 v[NTPL];
    float lar = 1.f, lai = 0.f, lxr = 0.f, lxi = 0.f;
#pragma unroll
    for (int m = 0; m < NTPL; ++m) {
        v[m] = agg[((size_t)b * NT + lane * NTPL + m) * DIM + d];
        float nar = v[m].x * lar - v[m].y * lai;
        float nai = v[m].x * lai + v[m].y * lar;
        float nxr = v[m].x * lxr - v[m].y * lxi + v[m].z;
        float nxi = v[m].x * lxi + v[m].y * lxr + v[m].w;
        lar = nar; lai = nai; lxr = nxr; lxi = nxi;
    }

    float ar = lar, ai = lai, xr = lxr, xi = lxi;
#pragma unroll
    for (int off = 1; off < 64; off <<= 1) {
        float par = __shfl_up(ar, (unsigned)off, 64);
        float pai = __shfl_up(ai, (unsigned)off, 64);
        float pxr = __shfl_up(xr, (unsigned)off, 64);
        float pxi = __shfl_up(xi, (unsigned)off, 64);
        if (lane >= off) {
            float nar = ar * par - ai * pai;
            float nai = ar * pai + ai * par;
            float nxr = ar * pxr - ai * pxi + xr;
            float nxi = ar * pxi + ai * pxr + xi;
            ar = nar; ai = nai; xr = nxr; xi = nxi;
        }
    }

    float ear = __shfl_up(ar, 1u, 64);
    float eai = __shfl_up(ai, 1u, 64);
    float exr = __shfl_up(xr, 1u, 64);
    float exi = __shfl_up(xi, 1u, 64);
    if (lane == 0) { ear = 1.f; eai = 0.f; exr = 0.f; exi = 0.f; }

#pragma unroll
    for (int m = 0; m < NTPL; ++m) {
        seed[((size_t)b * NT + lane * NTPL + m) * DIM + d] =
            make_float2(exr, exi);
        float nar = v[m].x * ear - v[m].y * eai;
        float nai = v[m].x * eai + v[m].y * ear;
        float nxr = v[m].x * exr - v[m].y * exi + v[m].z;
        float nxi = v[m].x * exi + v[m].y * exr + v[m].w;
        ear = nar; eai = nai; exr = nxr; exi = nxi;
    }
}

// ---------------------------------------------------------------------------
// Kernel 3: float2 seed, plain float4 stores.
// ---------------------------------------------------------------------------
template <int NT, int T>
__global__ __launch_bounds__(256, 8) void k_apply(
    const float* __restrict__ Ar, const float* __restrict__ Ai,
    const float* __restrict__ Xr, const float* __restrict__ Xi,
    const float2* __restrict__ seed, float* __restrict__ outf)
{
    int half = threadIdx.x >> 7;
    int wl   = threadIdx.x & 127;
    int tile = blockIdx.x * 2 + half;
    int b = tile / NT;
    int j = tile - b * NT;
    int d = wl * 2;

    float yr[2], yi[2];
    size_t o = ((size_t)b * NT + j) * DIM + d;
    {
        float2 s0 = seed[o];
        float2 s1 = seed[o + 1];
        yr[0] = s0.x; yi[0] = s0.y;
        yr[1] = s1.x; yi[1] = s1.y;
    }

    size_t base = ((size_t)b * SEQ + (size_t)j * T) * DIM + d;

#pragma unroll
    for (int t = 0; t < T; ++t) {
        size_t idx = base + (size_t)t * DIM;
        float2 a_re = *(const float2*)(Ar + idx);
        float2 a_im = *(const float2*)(Ai + idx);
        float2 x_re = *(const float2*)(Xr + idx);
        float2 x_im = *(const float2*)(Xi + idx);
        const float* par = (const float*)&a_re;
        const float* pai = (const float*)&a_im;
        const float* pxr = (const float*)&x_re;
        const float* pxi = (const float*)&x_im;
#pragma unroll
        for (int k = 0; k < 2; ++k) {
            float nyr = par[k] * yr[k] - pai[k] * yi[k] + pxr[k];
            float nyi = par[k] * yi[k] + pai[k] * yr[k] + pxi[k];
            yr[k] = nyr; yi[k] = nyi;
        }
        *(float4*)(outf + 2 * idx) = make_float4(yr[0], yi[0], yr[1], yi[1]);
    }
}

// ===========================================================================
// Fallback 3-kernel path (small workspace) — NT=64, self-contained.
// ===========================================================================
template <int NT, int T>
__global__ __launch_bounds__(256) void k_tile_agg_fb(
    const float* __restrict__ Ar, const float* __restrict__ Ai,
    const float* __restrict__ Xr, const float* __restrict__ Xi,
    float4* __restrict__ agg)
{
    int wave = threadIdx.x >> 6;
    int lane = threadIdx.x & 63;
    int tile = blockIdx.x * 4 + wave;
    int b = tile / NT;
    int j = tile - b * NT;
    int d = lane * 4;

    size_t base = ((size_t)b * SEQ + (size_t)j * T) * DIM + d;

    float pr[4], pi[4], yr[4], yi[4];
#pragma unroll
    for (int k = 0; k < 4; ++k) { pr[k] = 1.f; pi[k] = 0.f; yr[k] = 0.f; yi[k] = 0.f; }

#pragma unroll 4
    for (int t = 0; t < T; ++t) {
        size_t idx = base + (size_t)t * DIM;
        float4 a_re = *(const float4*)(Ar + idx);
        float4 a_im = *(const float4*)(Ai + idx);
        float4 x_re = *(const float4*)(Xr + idx);
        float4 x_im = *(const float4*)(Xi + idx);
        const float* par = (const float*)&a_re;
        const float* pai = (const float*)&a_im;
        const float* pxr = (const float*)&x_re;
        const float* pxi = (const float*)&x_im;
#pragma unroll
        for (int k = 0; k < 4; ++k) {
            float a_r = par[k], a_i = pai[k];
            float npr = a_r * pr[k] - a_i * pi[k];
            float npi = a_r * pi[k] + a_i * pr[k];
            pr[k] = npr; pi[k] = npi;
            float nyr = a_r * yr[k] - a_i * yi[k] + pxr[k];
            float nyi = a_r * yi[k] + a_i * yr[k] + pxi[k];
            yr[k] = nyr; yi[k] = nyi;
        }
    }

    size_t o = ((size_t)b * NT + j) * DIM + d;
#pragma unroll
    for (int k = 0; k < 4; ++k)
        agg[o + k] = make_float4(pr[k], pi[k], yr[k], yi[k]);
}

template <int NT>
__global__ __launch_bounds__(256) void k_scan_agg_fb(float4* __restrict__ agg)
{
    constexpr int NTPL = NT / 64;
    int lane = threadIdx.x & 63;
    int col  = blockIdx.x * 4 + (threadIdx.x >> 6);
    int b = col >> 8;
    int d = col & 255;

    float4 v[NTPL];
    float lar = 1.f, lai = 0.f, lxr = 0.f, lxi = 0.f;
#pragma unroll
    for (int m = 0; m < NTPL; ++m) {
        v[m] = agg[((size_t)b * NT + lane * NTPL + m) * DIM + d];
        float nar = v[m].x * lar - v[m].y * lai;
        float nai = v[m].x * lai + v[m].y * lar;
        float nxr = v[m].x * lxr - v[m].y * lxi + v[m].z;
        float nxi = v[m].x * lxi + v[m].y * lxr + v[m].w;
        lar = nar; lai = nai; lxr = nxr; lxi = nxi;
    }

    float ar = lar, ai = lai, xr = lxr, xi = lxi;
#pragma unroll
    for (int off = 1; off < 64; off <<= 1) {
        float par = __shfl_up(ar, (unsigned)off, 64);
        float pai = __shfl_up(ai, (unsigned)off, 64);
        float pxr = __shfl_up(xr, (unsigned)off, 64);
        float pxi = __shfl_up(xi, (unsigned)off, 64);
        if (lane >= off) {
            float nar = ar * par - ai * pai;
            float nai = ar * pai + ai * par;
            float nxr = ar * pxr - ai * pxi + xr;
            float nxi = ar * pxi + ai * pxr + xi;
            ar = nar; ai = nai; xr = nxr; xi = nxi;
        }
    }

    float ear = __shfl_up(ar, 1u, 64);
    float eai = __shfl_up(ai, 1u, 64);
    float exr = __shfl_up(xr, 1u, 64);
    float exi = __shfl_up(xi, 1u, 64);
    if (lane == 0) { ear = 1.f; eai = 0.f; exr = 0.f; exi = 0.f; }

#pragma unroll
    for (int m = 0; m < NTPL; ++m) {
        agg[((size_t)b * NT + lane * NTPL + m) * DIM + d] =
            make_float4(exr, exi, 0.f, 0.f);
        float nar = v[m].x * ear - v[m].y * eai;
        float nai = v[m].x * eai + v[m].y * ear;
        float nxr = v[m].x * exr - v[m].y * exi + v[m].z;
        float nxi = v[m].x * exi + v[m].y * exr + v[m].w;
        ear = nar; eai = nai; exr = nxr; exi = nxi;
    }
}

template <int NT, int T>
__global__ __launch_bounds__(256, 8) void k_apply_fb(
    const float* __restrict__ Ar, const float* __restrict__ Ai,
    const float* __restrict__ Xr, const float* __restrict__ Xi,
    const float4* __restrict__ agg, float* __restrict__ outf)
{
    int half = threadIdx.x >> 7;
    int wl   = threadIdx.x & 127;
    int tile = blockIdx.x * 2 + half;
    int b = tile / NT;
    int j = tile - b * NT;
    int d = wl * 2;

    float yr[2], yi[2];
    size_t o = ((size_t)b * NT + j) * DIM + d;
    {
        float4 p0 = agg[o];
        float4 p1 = agg[o + 1];
        yr[0] = p0.x; yi[0] = p0.y;
        yr[1] = p1.x; yi[1] = p1.y;
    }

    size_t base = ((size_t)b * SEQ + (size_t)j * T) * DIM + d;

#pragma unroll
    for (int t = 0; t < T; ++t) {
        size_t idx = base + (size_t)t * DIM;
        float2 a_re = *(const float2*)(Ar + idx);
        float2 a_im = *(const float2*)(Ai + idx);
        float2 x_re = *(const float2*)(Xr + idx);
        float2 x_im = *(const float2*)(Xi + idx);
        const float* par = (const float*)&a_re;
        const float* pai = (const float*)&a_im;
        const float* pxr = (const float*)&x_re;
        const float* pxi = (const float*)&x_im;
#pragma unroll
        for (int k = 0; k < 2; ++k) {
            float nyr = par[k] * yr[k] - pai[k] * yi[k] + pxr[k];
            float nyi = par[k] * yi[k] + pai[k] * yr[k] + pxi[k];
            yr[k] = nyr; yi[k] = nyi;
        }
        *(float4*)(outf + 2 * idx) = make_float4(yr[0], yi[0], yr[1], yi[1]);
    }
}

extern "C" void kernel_launch(void* const* d_in, const int* in_sizes, int n_in,
                              void* d_out, int out_size, void* d_ws, size_t ws_size,
                              hipStream_t stream)
{
    const float* Ar = (const float*)d_in[0];
    const float* Ai = (const float*)d_in[1];
    const float* Xr = (const float*)d_in[2];
    const float* Xi = (const float*)d_in[3];
    float* outf = (float*)d_out;

    dim3 block(256);

    if (ws_size >= AGG_BYTES + SEED_BYTES) {
        constexpr int NT = NT_MAIN, T = T_MAIN;        // 256 / 16
        float4* agg  = (float4*)d_ws;
        float2* seed = (float2*)((char*)d_ws + AGG_BYTES);
        dim3 gridP(NSUB_TOT / NSUB_BLK);               // 1024 blocks, 4/CU
        dim3 grid3((BATCH * NT) / 2);                  // k3: 2 waves/tile
        k_tile_agg_pipe<<<gridP, block, 0, stream>>>(Ar, Ai, Xr, Xi, agg);
        k_scan_agg<NT><<<(BATCH * DIM) / 4, block, 0, stream>>>(agg, seed);
        k_apply<NT, T><<<grid3, block, 0, stream>>>(Ar, Ai, Xr, Xi, seed, outf);
    } else {
        constexpr int NT = 64, T = SEQ / 64;
        float4* agg = (float4*)d_ws;
        dim3 grid1((BATCH * NT) / 4);
        dim3 grid3((BATCH * NT) / 2);
        k_tile_agg_fb<NT, T><<<grid1, block, 0, stream>>>(Ar, Ai, Xr, Xi, agg);
        k_scan_agg_fb<NT><<<(BATCH * DIM) / 4, block, 0, stream>>>(agg);
        k_apply_fb<NT, T><<<grid3, block, 0, stream>>>(Ar, Ai, Xr, Xi, agg, outf);
    }
}